// Round 2
// baseline (841.981 us; speedup 1.0000x reference)
//
#include <hip/hip_runtime.h>
#include <hip/hip_cooperative_groups.h>

// GcnEncoderGraph fully-fused pipeline. B=8, N=2048, DIN=32, DH=DE=64, R=3.
// R9: ONE cooperative dispatch (256 blocks x 512 thr, 1 block/CU co-resident)
// replaces the 7-dispatch chain; 6 grid.sync()s replace dispatch boundaries.
// Theory: per-kernel roofline sums to ~65-90us but dur_us was 355us with no
// single dispatch >77us -> inter-dispatch overhead dominated. Fusing also
// forces the pipeline into rocprof's top-5 so we finally see its counters.
// Stage content carried from R8: LDS nibble-LUT mask expansion, 2-barrier
// parallel combine, union bitplane, fused BN+xw, LDS tail matvec.

#define NN 2048
#define PLANE_W 1048576L  // u32 words per bitplane: 8*2048*64

namespace cg = cooperative_groups;

typedef short short8 __attribute__((ext_vector_type(8)));
typedef float floatx4 __attribute__((ext_vector_type(4)));

__device__ __forceinline__ unsigned short f2bf(float x) {
  unsigned u = __float_as_uint(x);
  u += 0x7FFFu + ((u >> 16) & 1u);
  return (unsigned short)(u >> 16);
}

// ---------- stage 0a: XW precompute (layer 1), 512-thread unit ---------------
__device__ void dev_xw_first512(char* smemc, int u, int tid,
                                const float* __restrict__ x,
                                const float* __restrict__ w,
                                unsigned short* __restrict__ xws) {
  float* xs = (float*)smemc;                   // [64][33]
  float* wsh = (float*)(smemc + 64 * 33 * 4);  // [32][64]
  const int jc = u & 31, b = (u >> 5) & 7, r = u >> 8;
  const int j0 = jc * 64;
  for (int idx = tid; idx < 64 * 32; idx += 512) {
    int row = idx >> 5, f = idx & 31;
    xs[row * 33 + f] = x[((long)b * NN + j0 + row) * 32 + f];
    wsh[idx] = w[r * 2048 + idx];  // [f][e]
  }
  __syncthreads();
  const int j = tid & 63, gg = tid >> 6;  // gg in [0,8)
  const int g = gg & 3, hf = gg >> 2;
  const int k = j0 + j;
  const int kblk = k >> 5, kq = (k >> 3) & 3, kj = k & 7;
  unsigned short* dst =
      xws + (((long)(r * 8 + b) * 64 + kblk) * 4 + g) * 512 + kj;
  float xr[32];
#pragma unroll
  for (int f = 0; f < 32; ++f) xr[f] = xs[j * 33 + f];
#pragma unroll
  for (int ii = 0; ii < 8; ++ii) {
    float acc = 0.f;
#pragma unroll
    for (int f = 0; f < 32; ++f)
      acc += xr[f] * wsh[f * 64 + g * 16 + hf * 8 + ii];
    dst[(kq * 16 + hf * 8 + ii) * 8] = f2bf(acc);
  }
  __syncthreads();
}

// ---------- masked MFMA gemm stage (8 waves interleave K, fused epilogue) ----
// b = bid&7 (XCD affinity), it = bid>>3. Wave w covers kblks == w (mod 8).
// Mask bits expand to bf16 A-frags via 16-entry LDS LUT (conflict-free).
// Combine: 2-barrier [rs][src][t][lane] redistribution, 4-wave epilogue.
template <int NREL, bool RELU, bool POOL3>
__device__ void dev_gemm8(char* smem, int bid, int tid,
                          const unsigned* __restrict__ planes,
                          const unsigned short* __restrict__ xws,
                          const float* __restrict__ bias,
                          float* __restrict__ Hout,
                          float* __restrict__ part3) {
  constexpr int MASK_BYTES = NREL * 8448;  // [NREL][64 rows][33 words]
  unsigned* mw = (unsigned*)smem;
  uint2* lut = (uint2*)(smem + MASK_BYTES);  // 16 x 8B nibble->2x bf16-pair
  floatx4* cb = (floatx4*)smem;              // 64 KB combine buffer (overlay)
  const int b = bid & 7, it = bid >> 3;
  const int wave = tid >> 6, lane = tid & 63;
  const int m = lane & 15, kq = lane >> 4;
  const unsigned shamt = kq * 8;
  const int i0 = it * 64;

  if (tid < 16) {
    unsigned n = tid;
    lut[n] =
        make_uint2(((n & 1u) ? 0x3f80u : 0u) | ((n & 2u) ? 0x3f800000u : 0u),
                   ((n & 4u) ? 0x3f80u : 0u) | ((n & 8u) ? 0x3f800000u : 0u));
  }

  floatx4 acc[4][4];  // [rowset][t]
#pragma unroll
  for (int rs = 0; rs < 4; ++rs)
#pragma unroll
    for (int t = 0; t < 4; ++t) acc[rs][t] = floatx4{0, 0, 0, 0};

  for (int chunk = 0; chunk < 2; ++chunk) {
    for (int idx = tid; idx < NREL * 2048; idx += 512) {
      int p = idx >> 11, rem = idx & 2047, row = rem >> 5, w = rem & 31;
      long g = ((long)b * NN + i0 + row) * 64 + chunk * 32 + w;
      unsigned v;
      if (NREL == 3)
        v = planes[(long)p * PLANE_W + g];
      else
        v = planes[3 * PLANE_W + g];  // precomputed union plane
      mw[(p * 64 + row) * 33 + w] = v;
    }
    __syncthreads();
#pragma unroll
    for (int j = 0; j < 4; ++j) {
      const int kk = j * 8 + wave;       // chunk-local kblk
      const int kblk = chunk * 32 + kk;  // global kblk
#pragma unroll
      for (int p = 0; p < NREL; ++p) {
        const unsigned short* bb =
            xws + ((long)(p * 8 + b) * 64 + kblk) * 2048 + lane * 8;
        short8 bf0 = *(const short8*)(bb);
        short8 bf1 = *(const short8*)(bb + 512);
        short8 bf2 = *(const short8*)(bb + 1024);
        short8 bf3 = *(const short8*)(bb + 1536);
#pragma unroll
        for (int rs = 0; rs < 4; ++rs) {
          unsigned word = mw[(p * 64 + rs * 16 + m) * 33 + kk];
          unsigned byte = (word >> shamt) & 0xffu;
          uint2 lo = lut[byte & 15u];  // ds_read_b64, conflict-free
          uint2 hi = lut[byte >> 4];
          union {
            unsigned uu[4];
            short8 s8;
          } fr;
          fr.uu[0] = lo.x;
          fr.uu[1] = lo.y;
          fr.uu[2] = hi.x;
          fr.uu[3] = hi.y;
          acc[rs][0] = __builtin_amdgcn_mfma_f32_16x16x32_bf16(
              fr.s8, bf0, acc[rs][0], 0, 0, 0);
          acc[rs][1] = __builtin_amdgcn_mfma_f32_16x16x32_bf16(
              fr.s8, bf1, acc[rs][1], 0, 0, 0);
          acc[rs][2] = __builtin_amdgcn_mfma_f32_16x16x32_bf16(
              fr.s8, bf2, acc[rs][2], 0, 0, 0);
          acc[rs][3] = __builtin_amdgcn_mfma_f32_16x16x32_bf16(
              fr.s8, bf3, acc[rs][3], 0, 0, 0);
        }
      }
    }
    __syncthreads();
  }

  // --- combine: phase A — waves 4..7 write slots [rs][src][t][lane] ---
  if (wave >= 4) {
    const int src = wave - 4;
#pragma unroll
    for (int rs = 0; rs < 4; ++rs)
#pragma unroll
      for (int t = 0; t < 4; ++t)
        cb[((rs * 4 + src) * 4 + t) * 64 + lane] = acc[rs][t];
  }
  __syncthreads();
  // phase B — waves 0..3 fold their acc into their slot (exclusive RMW)
  if (wave < 4) {
#pragma unroll
    for (int rs = 0; rs < 4; ++rs)
#pragma unroll
      for (int t = 0; t < 4; ++t) {
        const int ix = ((rs * 4 + wave) * 4 + t) * 64 + lane;
        cb[ix] = cb[ix] + acc[rs][t];
      }
  }
  __syncthreads();
  // phase C — wave w sums 4 slots of rowset w, epilogue for its 16 rows
  if (wave < 4) {
    const int rs = wave;
    floatx4 s[4];
#pragma unroll
    for (int t = 0; t < 4; ++t) s[t] = cb[((rs * 4 + 0) * 4 + t) * 64 + lane];
#pragma unroll
    for (int src = 1; src < 4; ++src)
#pragma unroll
      for (int t = 0; t < 4; ++t)
        s[t] += cb[((rs * 4 + src) * 4 + t) * 64 + lane];
    float bv[4];
#pragma unroll
    for (int t = 0; t < 4; ++t) bv[t] = bias[t * 16 + m];
    float pmt[4] = {-3.4e38f, -3.4e38f, -3.4e38f, -3.4e38f};
#pragma unroll
    for (int reg = 0; reg < 4; ++reg) {
#pragma unroll
      for (int t = 0; t < 4; ++t) s[t][reg] += bv[t];
      float q = s[0][reg] * s[0][reg] + s[1][reg] * s[1][reg] +
                s[2][reg] * s[2][reg] + s[3][reg] * s[3][reg];
#pragma unroll
      for (int off = 1; off <= 8; off <<= 1) q += __shfl_xor(q, off);
      q = 1.0f / fmaxf(sqrtf(q), 1e-12f);
#pragma unroll
      for (int t = 0; t < 4; ++t) {
        float o = s[t][reg] * q;
        if (RELU) o = fmaxf(o, 0.0f);
        if (POOL3)
          pmt[t] = fmaxf(pmt[t], o);
        else
          Hout[((long)b * NN + i0 + rs * 16 + kq * 4 + reg) * 64 + t * 16 +
               m] = o;
      }
    }
    if (POOL3) {
#pragma unroll
      for (int t = 0; t < 4; ++t) {
        pmt[t] = fmaxf(pmt[t], __shfl_xor(pmt[t], 16));
        pmt[t] = fmaxf(pmt[t], __shfl_xor(pmt[t], 32));
      }
      float* pm = (float*)(smem + wave * 16384);
      if (kq == 0) {
#pragma unroll
        for (int t = 0; t < 4; ++t) pm[t * 16 + m] = pmt[t];
      }
    }
  }
  if (POOL3) {
    __syncthreads();
    if (tid < 64) {
      float v = -3.4e38f;
#pragma unroll
      for (int w = 0; w < 4; ++w)
        v = fmaxf(v, ((const float*)(smem + w * 16384))[tid]);
      part3[((long)b * 32 + it) * 64 + tid] = v;
    }
  }
}

// ---------- fused BN + xw_h (+pool partial from b==0 blocks), 512 thr --------
// block (jc = bid&31, b = bid>>5). BN stats per node over (bb,e) from H
// directly; HBN never materialized.
__device__ void dev_xwh_bn512(char* smemc, int bid, int tid,
                              const float* __restrict__ H,
                              const float* __restrict__ w,
                              unsigned short* __restrict__ xws,
                              float* __restrict__ PP) {
  float* hs = (float*)smemc;                        // [64][65]
  float* wsh = (float*)(smemc + 16640);             // [64][64]
  float* sm = (float*)(smemc + 16640 + 16384);      // [64]
  float* srs = (float*)(smemc + 16640 + 16384 + 256);
  const int jc = bid & 31, b = bid >> 5;
  const int j0 = jc * 64;
  // pass 1: stats. thread t: node n=t>>3, octant o=t&7 (8 e each, all 8 bb)
  {
    const int n = tid >> 3, o = tid & 7;
    float s1 = 0.f, s2 = 0.f;
#pragma unroll
    for (int bb = 0; bb < 8; ++bb) {
      const float4* hp =
          (const float4*)(H + ((long)bb * NN + j0 + n) * 64 + o * 8);
#pragma unroll
      for (int c = 0; c < 2; ++c) {
        float4 v = hp[c];
        s1 += v.x + v.y + v.z + v.w;
        s2 += v.x * v.x + v.y * v.y + v.z * v.z + v.w * v.w;
      }
    }
    s1 += __shfl_xor(s1, 1);
    s2 += __shfl_xor(s2, 1);
    s1 += __shfl_xor(s1, 2);
    s2 += __shfl_xor(s2, 2);
    s1 += __shfl_xor(s1, 4);
    s2 += __shfl_xor(s2, 4);
    if (o == 0) {
      float mean = s1 * (1.0f / 512.0f);
      float var = fmaxf(s2 * (1.0f / 512.0f) - mean * mean, 0.0f);
      sm[n] = mean;
      srs[n] = rsqrtf(var + 1e-5f);
    }
  }
  __syncthreads();
  // pass 2: normalized tile for our b + weights
  for (int idx = tid; idx < 4096; idx += 512) {
    int row = idx >> 6, f = idx & 63;
    float v = H[((long)b * NN + j0 + row) * 64 + f];
    hs[row * 65 + f] = (v - sm[row]) * srs[row];
    wsh[idx] = w[idx];
  }
  __syncthreads();
  // pass 3: xw into swizzled fragment layout (8 e-cols per thread)
  {
    const int j = tid & 63, gg = tid >> 6;
    const int g = gg & 3, hf = gg >> 2;
    const int k = j0 + j;
    const int kblk = k >> 5, kq = (k >> 3) & 3, kj = k & 7;
    unsigned short* dst = xws + (((long)b * 64 + kblk) * 4 + g) * 512 + kj;
    float acc[8];
#pragma unroll
    for (int ii = 0; ii < 8; ++ii) acc[ii] = 0.f;
#pragma unroll
    for (int c = 0; c < 4; ++c) {
      float xr[16];
#pragma unroll
      for (int f = 0; f < 16; ++f) xr[f] = hs[j * 65 + c * 16 + f];
#pragma unroll
      for (int ii = 0; ii < 8; ++ii)
#pragma unroll
        for (int f = 0; f < 16; ++f)
          acc[ii] += xr[f] * wsh[(c * 16 + f) * 64 + g * 16 + hf * 8 + ii];
    }
#pragma unroll
    for (int ii = 0; ii < 8; ++ii)
      dst[(kq * 16 + hf * 8 + ii) * 8] = f2bf(acc[ii]);
  }
  // pass 4 (b==0 blocks): pool partials over our 64 nodes, all (bb,e)
  if (b == 0) {
    const int col = tid;  // 512 = 8 bb x 64 e
    const int bb = col >> 6, e = col & 63;
    float mx = -3.4e38f;
    for (int n = 0; n < 64; ++n) {
      float v = H[((long)bb * NN + j0 + n) * 64 + e];
      mx = fmaxf(mx, (v - sm[n]) * srs[n]);
    }
    PP[(long)jc * 512 + col] = mx;
  }
  __syncthreads();
}

// ---------- tail: pool finals + linear head (block 0 only) -------------------
__device__ void dev_tail(char* smemc, int tid, const float* __restrict__ PP1,
                         const float* __restrict__ PP2,
                         const float* __restrict__ P3,
                         float* __restrict__ out,
                         const float* __restrict__ wmap,
                         const float* __restrict__ bmap) {
  float* obuf = (float*)smemc;  // [8][192]
  const int col = tid;
  const int bb = col >> 6, e = col & 63;
  float m1 = -3.4e38f, m2 = -3.4e38f, m3 = -3.4e38f;
#pragma unroll
  for (int c = 0; c < 32; ++c) {
    m1 = fmaxf(m1, PP1[(long)c * 512 + col]);
    m2 = fmaxf(m2, PP2[(long)c * 512 + col]);
    m3 = fmaxf(m3, P3[((long)bb * 32 + c) * 64 + e]);
  }
  out[bb * 192 + e] = m1;
  out[bb * 192 + 64 + e] = m2;
  out[bb * 192 + 128 + e] = m3;
  obuf[bb * 192 + e] = m1;
  obuf[bb * 192 + 64 + e] = m2;
  obuf[bb * 192 + 128 + e] = m3;
  __syncthreads();
  float acc = bmap[e];
#pragma unroll 4
  for (int k = 0; k < 192; ++k) acc += obuf[bb * 192 + k] * wmap[k * 64 + e];
  out[1536 + bb * 64 + e] = acc;
}

// ---------- the single fused cooperative kernel ------------------------------
__global__ __launch_bounds__(512) void k_fused(
    const int* __restrict__ rel, const float* __restrict__ x,
    const float* __restrict__ w_first, const float* __restrict__ b_first,
    const float* __restrict__ w_block, const float* __restrict__ b_block,
    const float* __restrict__ w_last, const float* __restrict__ b_last,
    const float* __restrict__ wmap, const float* __restrict__ bmap,
    unsigned* __restrict__ planes, unsigned short* __restrict__ xws,
    float* __restrict__ H, float* __restrict__ PP1, float* __restrict__ PP2,
    float* __restrict__ PART3, float* __restrict__ out) {
  __shared__ __align__(16) char smem[65536];
  cg::grid_group grid = cg::this_grid();
  const int bid = blockIdx.x, tid = threadIdx.x;

  // ---- stage 0: XW(layer1) (3 units/block) + pack bitplanes (+union) ----
#pragma unroll
  for (int s = 0; s < 3; ++s)
    dev_xw_first512(smem, bid * 3 + s, tid, x, w_first, xws);
  for (long t = (long)bid * 512 + tid; t < 1048576L; t += 131072L) {
    int w32 = (int)(t & 63);
    long bi = t >> 6;  // b*2048 + i
    const int4* rp = (const int4*)(rel + bi * NN + w32 * 32);
    unsigned m0 = 0, m1 = 0, m2 = 0;
#pragma unroll
    for (int c = 0; c < 8; ++c) {
      int4 v = rp[c];
      int vv[4] = {v.x, v.y, v.z, v.w};
#pragma unroll
      for (int j = 0; j < 4; ++j) {
        unsigned b1 = 1u << (c * 4 + j);
        m0 |= (vv[j] == 1) ? b1 : 0u;
        m1 |= (vv[j] == 2) ? b1 : 0u;
        m2 |= (vv[j] == 3) ? b1 : 0u;
      }
    }
    long o = bi * 64 + w32;
    planes[o] = m0;
    planes[PLANE_W + o] = m1;
    planes[2 * PLANE_W + o] = m2;
    planes[3 * PLANE_W + o] = m0 | m1 | m2;  // union plane for gemm2/3
  }
  __threadfence();
  grid.sync();
  // ---- layer 1 gemm (fused bias+L2norm+relu) ----
  dev_gemm8<3, true, false>(smem, bid, tid, planes, xws, b_first, H, nullptr);
  __threadfence();
  grid.sync();
  dev_xwh_bn512(smem, bid, tid, H, w_block, xws, PP1);
  __threadfence();
  grid.sync();
  // ---- layer 2 ----
  dev_gemm8<1, true, false>(smem, bid, tid, planes, xws, b_block, H, nullptr);
  __threadfence();
  grid.sync();
  dev_xwh_bn512(smem, bid, tid, H, w_last, xws, PP2);
  __threadfence();
  grid.sync();
  // ---- layer 3 (fused L2norm + pool3 partial) ----
  dev_gemm8<1, false, true>(smem, bid, tid, planes, xws, b_last, nullptr,
                            PART3);
  __threadfence();
  grid.sync();
  // ---- pool finals + head ----
  if (bid == 0) dev_tail(smem, tid, PP1, PP2, PART3, out, wmap, bmap);
}

extern "C" void kernel_launch(void* const* d_in, const int* in_sizes, int n_in,
                              void* d_out, int out_size, void* d_ws,
                              size_t ws_size, hipStream_t stream) {
  const float* x = (const float*)d_in[0];
  const int* rel = (const int*)d_in[1];
  // d_in[2] (adj) unread: adj == (rel > 0) == union bitplane
  const float* w_first = (const float*)d_in[3];
  const float* b_first = (const float*)d_in[4];
  const float* w_block = (const float*)d_in[5];
  const float* b_block = (const float*)d_in[6];
  const float* w_last = (const float*)d_in[7];
  const float* b_last = (const float*)d_in[8];
  const float* w_map = (const float*)d_in[9];
  const float* b_map = (const float*)d_in[10];
  float* out = (float*)d_out;

  char* ws = (char*)d_ws;
  const size_t MB = 1024 * 1024;
  unsigned* PLANES = (unsigned*)(ws);                     // 16 MiB (4 planes)
  unsigned short* XWS = (unsigned short*)(ws + 16 * MB);  // 6 MiB
  float* H = (float*)(ws + 22 * MB);                      // 4 MiB
  float* PP1 = (float*)(ws + 26 * MB);                    // 64 KiB
  float* PP2 = (float*)(ws + 27 * MB);                    // 64 KiB
  float* PART3 = (float*)(ws + 28 * MB);                  // 64 KiB

  void* kargs[] = {&rel,    &x,      &w_first, &b_first, &w_block, &b_block,
                   &w_last, &b_last, &w_map,   &b_map,   &PLANES,  &XWS,
                   &H,      &PP1,    &PP2,     &PART3,   &out};
  hipLaunchCooperativeKernel((void*)k_fused, dim3(256), dim3(512), kargs, 0,
                             stream);
}

// Round 3
// 409.860 us; speedup vs baseline: 2.0543x; 2.0543x over previous
//
#include <hip/hip_runtime.h>

// GcnEncoderGraph multi-kernel pipeline. B=8, N=2048, DIN=32, DH=DE=64, R=3.
// R10: revert cooperative fusion (R9 counters: 617us with MfmaUtil 1.4%,
// VALUBusy 4.3% -> ~550us stall in cg grid.sync; harness floor ~225us of
// fills inside timed window; our kernels were ~130us in R8).
// vs R8: (1) pack kernel eliminated — gemm1 reads rel directly, builds mask
// words via __ballot (1 coalesced load + 4 cmp/ballot per 64 edges), writes
// only the 4MB union plane for gemm2/3; (2) tail fused into gemm3 via
// last-block atomic counter (zeroed in k_xw1); (3) 6 dispatches (was 7):
// xw1, gemm1(rel-direct), bn1, gemm2, bn2, gemm3+tail.

#define NN 2048

typedef short short8 __attribute__((ext_vector_type(8)));
typedef float floatx4 __attribute__((ext_vector_type(4)));

__device__ __forceinline__ unsigned short f2bf(float x) {
  unsigned u = __float_as_uint(x);
  u += 0x7FFFu + ((u >> 16) & 1u);
  return (unsigned short)(u >> 16);
}

// ---------- kernel 1: XW precompute (layer 1), swizzled B-fragment order -----
// 768 blocks x 256 thr; block 0 also zeros the gemm3 done-counter.
__global__ __launch_bounds__(256) void k_xw1(const float* __restrict__ x,
                                             const float* __restrict__ w,
                                             unsigned short* __restrict__ xws,
                                             unsigned* __restrict__ done) {
  __shared__ __align__(16) char smemc[16640];
  const int u = blockIdx.x, tid = threadIdx.x;
  if (u == 0 && tid == 0) *done = 0u;
  float* xs = (float*)smemc;                   // [64][33]
  float* wsh = (float*)(smemc + 64 * 33 * 4);  // [32][64]
  const int jc = u & 31, b = (u >> 5) & 7, r = u >> 8;
  const int j0 = jc * 64;
  for (int idx = tid; idx < 64 * 32; idx += 256) {
    int row = idx >> 5, f = idx & 31;
    xs[row * 33 + f] = x[((long)b * NN + j0 + row) * 32 + f];
    wsh[idx] = w[r * 2048 + idx];  // [f][e]
  }
  __syncthreads();
  const int j = tid & 63, g = tid >> 6;
  const int k = j0 + j;
  const int kblk = k >> 5, kq = (k >> 3) & 3, kj = k & 7;
  unsigned short* dst =
      xws + (((long)(r * 8 + b) * 64 + kblk) * 4 + g) * 512 + kj;
  float xr[32];
#pragma unroll
  for (int f = 0; f < 32; ++f) xr[f] = xs[j * 33 + f];
#pragma unroll
  for (int ii = 0; ii < 16; ++ii) {
    float acc = 0.f;
#pragma unroll
    for (int f = 0; f < 32; ++f) acc += xr[f] * wsh[f * 64 + g * 16 + ii];
    dst[(kq * 16 + ii) * 8] = f2bf(acc);
  }
}

// ---------- shared epilogue: combine + bias + L2norm (+relu / pool) ----------
template <bool RELU, bool POOL3>
__device__ __forceinline__ void gemm_epilogue(
    char* smem, int b, int it, int tid, floatx4 (&acc)[4][4],
    const float* __restrict__ bias, float* __restrict__ Hout,
    float* __restrict__ part3) {
  floatx4* cb = (floatx4*)smem;  // 64 KB combine buffer (overlay)
  const int wave = tid >> 6, lane = tid & 63;
  const int m = lane & 15, kq = lane >> 4;
  const int i0 = it * 64;
  // phase A — waves 4..7 write slots [rs][src][t][lane]
  if (wave >= 4) {
    const int src = wave - 4;
#pragma unroll
    for (int rs = 0; rs < 4; ++rs)
#pragma unroll
      for (int t = 0; t < 4; ++t)
        cb[((rs * 4 + src) * 4 + t) * 64 + lane] = acc[rs][t];
  }
  __syncthreads();
  // phase B — waves 0..3 fold their acc into their slot (exclusive RMW)
  if (wave < 4) {
#pragma unroll
    for (int rs = 0; rs < 4; ++rs)
#pragma unroll
      for (int t = 0; t < 4; ++t) {
        const int ix = ((rs * 4 + wave) * 4 + t) * 64 + lane;
        cb[ix] = cb[ix] + acc[rs][t];
      }
  }
  __syncthreads();
  // phase C — wave w sums 4 slots of rowset w, epilogue for its 16 rows
  if (wave < 4) {
    const int rs = wave;
    floatx4 s[4];
#pragma unroll
    for (int t = 0; t < 4; ++t) s[t] = cb[((rs * 4 + 0) * 4 + t) * 64 + lane];
#pragma unroll
    for (int src = 1; src < 4; ++src)
#pragma unroll
      for (int t = 0; t < 4; ++t)
        s[t] += cb[((rs * 4 + src) * 4 + t) * 64 + lane];
    float bv[4];
#pragma unroll
    for (int t = 0; t < 4; ++t) bv[t] = bias[t * 16 + m];
    float pmt[4] = {-3.4e38f, -3.4e38f, -3.4e38f, -3.4e38f};
#pragma unroll
    for (int reg = 0; reg < 4; ++reg) {
#pragma unroll
      for (int t = 0; t < 4; ++t) s[t][reg] += bv[t];
      float q = s[0][reg] * s[0][reg] + s[1][reg] * s[1][reg] +
                s[2][reg] * s[2][reg] + s[3][reg] * s[3][reg];
#pragma unroll
      for (int off = 1; off <= 8; off <<= 1) q += __shfl_xor(q, off);
      q = 1.0f / fmaxf(sqrtf(q), 1e-12f);
#pragma unroll
      for (int t = 0; t < 4; ++t) {
        float o = s[t][reg] * q;
        if (RELU) o = fmaxf(o, 0.0f);
        if (POOL3)
          pmt[t] = fmaxf(pmt[t], o);
        else
          Hout[((long)b * NN + i0 + rs * 16 + kq * 4 + reg) * 64 + t * 16 +
               m] = o;
      }
    }
    if (POOL3) {
#pragma unroll
      for (int t = 0; t < 4; ++t) {
        pmt[t] = fmaxf(pmt[t], __shfl_xor(pmt[t], 16));
        pmt[t] = fmaxf(pmt[t], __shfl_xor(pmt[t], 32));
      }
      float* pm = (float*)(smem + wave * 16384);
      if (kq == 0) {
#pragma unroll
        for (int t = 0; t < 4; ++t) pm[t * 16 + m] = pmt[t];
      }
    }
  }
}

// ---------- MFMA inner phase over one staged chunk ---------------------------
template <int NREL>
__device__ __forceinline__ void gemm_chunk_mfma(
    const unsigned* mw, const uint2* lut, const unsigned short* __restrict__ xws,
    int b, int chunk, int wave, int lane, floatx4 (&acc)[4][4]) {
  const int m = lane & 15, kq = lane >> 4;
  const unsigned shamt = kq * 8;
#pragma unroll
  for (int j = 0; j < 4; ++j) {
    const int kk = j * 8 + wave;       // chunk-local kblk
    const int kblk = chunk * 32 + kk;  // global kblk
#pragma unroll
    for (int p = 0; p < NREL; ++p) {
      const unsigned short* bb =
          xws + ((long)(p * 8 + b) * 64 + kblk) * 2048 + lane * 8;
      short8 bf0 = *(const short8*)(bb);
      short8 bf1 = *(const short8*)(bb + 512);
      short8 bf2 = *(const short8*)(bb + 1024);
      short8 bf3 = *(const short8*)(bb + 1536);
#pragma unroll
      for (int rs = 0; rs < 4; ++rs) {
        unsigned word = mw[(p * 64 + rs * 16 + m) * 33 + kk];
        unsigned byte = (word >> shamt) & 0xffu;
        uint2 lo = lut[byte & 15u];  // ds_read_b64, conflict-free
        uint2 hi = lut[byte >> 4];
        union {
          unsigned uu[4];
          short8 s8;
        } fr;
        fr.uu[0] = lo.x;
        fr.uu[1] = lo.y;
        fr.uu[2] = hi.x;
        fr.uu[3] = hi.y;
        acc[rs][0] = __builtin_amdgcn_mfma_f32_16x16x32_bf16(fr.s8, bf0,
                                                             acc[rs][0], 0, 0, 0);
        acc[rs][1] = __builtin_amdgcn_mfma_f32_16x16x32_bf16(fr.s8, bf1,
                                                             acc[rs][1], 0, 0, 0);
        acc[rs][2] = __builtin_amdgcn_mfma_f32_16x16x32_bf16(fr.s8, bf2,
                                                             acc[rs][2], 0, 0, 0);
        acc[rs][3] = __builtin_amdgcn_mfma_f32_16x16x32_bf16(fr.s8, bf3,
                                                             acc[rs][3], 0, 0, 0);
      }
    }
  }
}

// ---------- kernel 2: layer-1 gemm, rel-direct (pack fused in) ---------------
// 256 blocks x 512 thr; b = bid&7 (XCD affinity), it = bid>>3.
// Staging: wave reads 64 consecutive rel ints (coalesced 256B), 4x __ballot
// packs 64 edges into 2 mask words per plane; lane 0 writes LDS + the union
// plane (8B) for gemm2/3. Then the NREL=3 MFMA phase as before.
__global__ __launch_bounds__(512) void k_gemm_rel(
    const int* __restrict__ rel, const unsigned short* __restrict__ xws,
    const float* __restrict__ bias, float* __restrict__ Hout,
    unsigned* __restrict__ pu) {
  __shared__ __align__(16) char smem[65536];
  unsigned* mw = (unsigned*)smem;            // [3][64][33] mask words
  uint2* lut = (uint2*)(smem + 3 * 8448);    // 16 x 8B nibble->2x bf16-pair
  const int bid = blockIdx.x;
  const int b = bid & 7, it = bid >> 3;
  const int tid = threadIdx.x;
  const int wave = tid >> 6, lane = tid & 63;
  const int i0 = it * 64;

  if (tid < 16) {
    unsigned n = tid;
    lut[n] =
        make_uint2(((n & 1u) ? 0x3f80u : 0u) | ((n & 2u) ? 0x3f800000u : 0u),
                   ((n & 4u) ? 0x3f80u : 0u) | ((n & 8u) ? 0x3f800000u : 0u));
  }

  floatx4 acc[4][4];
#pragma unroll
  for (int rs = 0; rs < 4; ++rs)
#pragma unroll
    for (int t = 0; t < 4; ++t) acc[rs][t] = floatx4{0, 0, 0, 0};

  for (int chunk = 0; chunk < 2; ++chunk) {
    // stage: 1024 units (64 rows x 16 word-pairs), 8 waves, 128 iters each
    for (int i = 0; i < 128; i += 4) {
      int vq[4];
#pragma unroll
      for (int q = 0; q < 4; ++q) {
        const int u = (i + q) * 8 + wave;
        const int row = u >> 4, wp = u & 15;
        vq[q] = rel[((long)b * NN + i0 + row) * NN + chunk * 1024 + wp * 64 +
                    lane];
      }
#pragma unroll
      for (int q = 0; q < 4; ++q) {
        const int u = (i + q) * 8 + wave;
        const int row = u >> 4, wp = u & 15;
        const int v = vq[q];
        unsigned long long b1 = __ballot(v == 1);
        unsigned long long b2 = __ballot(v == 2);
        unsigned long long b3 = __ballot(v == 3);
        unsigned long long bu = __ballot(v != 0);
        if (lane == 0) {
          const int wbase = row * 33 + wp * 2;
          mw[wbase] = (unsigned)b1;
          mw[wbase + 1] = (unsigned)(b1 >> 32);
          mw[2112 + wbase] = (unsigned)b2;
          mw[2112 + wbase + 1] = (unsigned)(b2 >> 32);
          mw[4224 + wbase] = (unsigned)b3;
          mw[4224 + wbase + 1] = (unsigned)(b3 >> 32);
          *(unsigned long long*)&pu[((long)b * NN + i0 + row) * 64 +
                                    chunk * 32 + wp * 2] = bu;
        }
      }
    }
    __syncthreads();
    gemm_chunk_mfma<3>(mw, lut, xws, b, chunk, wave, lane, acc);
    __syncthreads();
  }
  gemm_epilogue<true, false>(smem, b, it, tid, acc, bias, Hout, nullptr);
}

// ---------- kernels 4/6: union-plane gemm (+ fused tail when POOL3) ----------
template <bool RELU, bool POOL3>
__global__ __launch_bounds__(512) void k_gemm_u(
    const unsigned* __restrict__ pu, const unsigned short* __restrict__ xws,
    const float* __restrict__ bias, float* __restrict__ Hout,
    float* __restrict__ part3, const float* __restrict__ PP1,
    const float* __restrict__ PP2, float* __restrict__ out,
    const float* __restrict__ wmap, const float* __restrict__ bmap,
    unsigned* __restrict__ done) {
  __shared__ __align__(16) char smem[65536];
  __shared__ int s_last;
  unsigned* mw = (unsigned*)smem;          // [64][33]
  uint2* lut = (uint2*)(smem + 8448);      // 16 x 8B
  const int bid = blockIdx.x;
  const int b = bid & 7, it = bid >> 3;
  const int tid = threadIdx.x;
  const int wave = tid >> 6, lane = tid & 63;
  const int i0 = it * 64;

  if (tid < 16) {
    unsigned n = tid;
    lut[n] =
        make_uint2(((n & 1u) ? 0x3f80u : 0u) | ((n & 2u) ? 0x3f800000u : 0u),
                   ((n & 4u) ? 0x3f80u : 0u) | ((n & 8u) ? 0x3f800000u : 0u));
  }

  floatx4 acc[4][4];
#pragma unroll
  for (int rs = 0; rs < 4; ++rs)
#pragma unroll
    for (int t = 0; t < 4; ++t) acc[rs][t] = floatx4{0, 0, 0, 0};

  for (int chunk = 0; chunk < 2; ++chunk) {
    for (int idx = tid; idx < 2048; idx += 512) {
      int row = idx >> 5, w = idx & 31;
      mw[row * 33 + w] =
          pu[((long)b * NN + i0 + row) * 64 + chunk * 32 + w];
    }
    __syncthreads();
    gemm_chunk_mfma<1>(mw, lut, xws, b, chunk, wave, lane, acc);
    __syncthreads();
  }
  gemm_epilogue<RELU, POOL3>(smem, b, it, tid, acc, bias, Hout, part3);

  if (POOL3) {
    __syncthreads();
    if (tid < 64) {
      float v = -3.4e38f;
#pragma unroll
      for (int w = 0; w < 4; ++w)
        v = fmaxf(v, ((const float*)(smem + w * 16384))[tid]);
      part3[((long)b * 32 + it) * 64 + tid] = v;
    }
    // ---- fused tail: last block to finish runs pool finals + head ----
    __threadfence();
    __syncthreads();
    if (tid == 0) s_last = (atomicAdd(done, 1u) == 255u) ? 1 : 0;
    __syncthreads();
    if (s_last) {
      __threadfence();  // acquire: see all blocks' part3
      float* obuf = (float*)smem;  // [8][192] overlay
      const int col = tid;
      const int bb = col >> 6, e = col & 63;
      float m1 = -3.4e38f, m2 = -3.4e38f, m3 = -3.4e38f;
#pragma unroll
      for (int c = 0; c < 32; ++c) {
        m1 = fmaxf(m1, PP1[(long)c * 512 + col]);
        m2 = fmaxf(m2, PP2[(long)c * 512 + col]);
        m3 = fmaxf(m3, part3[((long)bb * 32 + c) * 64 + e]);
      }
      out[bb * 192 + e] = m1;
      out[bb * 192 + 64 + e] = m2;
      out[bb * 192 + 128 + e] = m3;
      obuf[bb * 192 + e] = m1;
      obuf[bb * 192 + 64 + e] = m2;
      obuf[bb * 192 + 128 + e] = m3;
      __syncthreads();
      float a = bmap[e];
#pragma unroll 4
      for (int k = 0; k < 192; ++k) a += obuf[bb * 192 + k] * wmap[k * 64 + e];
      out[1536 + bb * 64 + e] = a;
    }
  }
}

// ---------- kernels 3/5: fused BN + xw_h (+pool partial from b==0 blocks) ----
__global__ __launch_bounds__(256) void k_xwh_bn(const float* __restrict__ H,
                                                const float* __restrict__ w,
                                                unsigned short* __restrict__ xws,
                                                float* __restrict__ PP) {
  __shared__ float hs[64 * 65];
  __shared__ float wsh[64 * 64];
  __shared__ float sm[64], srs[64];
  const int bid = blockIdx.x, tid = threadIdx.x;
  const int jc = bid & 31, b = bid >> 5;
  const int j0 = jc * 64;
  // pass 1: stats. thread t: node n=t>>2, quarter q=t&3 (16 e each, all 8 bb)
  {
    const int n = tid >> 2, q = tid & 3;
    float s1 = 0.f, s2 = 0.f;
#pragma unroll
    for (int bb = 0; bb < 8; ++bb) {
      const float4* hp =
          (const float4*)(H + ((long)bb * NN + j0 + n) * 64 + q * 16);
#pragma unroll
      for (int c = 0; c < 4; ++c) {
        float4 v = hp[c];
        s1 += v.x + v.y + v.z + v.w;
        s2 += v.x * v.x + v.y * v.y + v.z * v.z + v.w * v.w;
      }
    }
    s1 += __shfl_xor(s1, 1);
    s2 += __shfl_xor(s2, 1);
    s1 += __shfl_xor(s1, 2);
    s2 += __shfl_xor(s2, 2);
    if (q == 0) {
      float mean = s1 * (1.0f / 512.0f);
      float var = fmaxf(s2 * (1.0f / 512.0f) - mean * mean, 0.0f);
      sm[n] = mean;
      srs[n] = rsqrtf(var + 1e-5f);
    }
  }
  __syncthreads();
  // pass 2: normalized tile for our b + weights
  for (int idx = tid; idx < 4096; idx += 256) {
    int row = idx >> 6, f = idx & 63;
    float v = H[((long)b * NN + j0 + row) * 64 + f];
    hs[row * 65 + f] = (v - sm[row]) * srs[row];
    wsh[idx] = w[idx];
  }
  __syncthreads();
  // pass 3: xw into swizzled fragment layout
  {
    const int j = tid & 63, g = tid >> 6;
    const int k = j0 + j;
    const int kblk = k >> 5, kq = (k >> 3) & 3, kj = k & 7;
    unsigned short* dst = xws + (((long)b * 64 + kblk) * 4 + g) * 512 + kj;
    float acc[16];
#pragma unroll
    for (int ii = 0; ii < 16; ++ii) acc[ii] = 0.f;
#pragma unroll
    for (int c = 0; c < 4; ++c) {
      float xr[16];
#pragma unroll
      for (int f = 0; f < 16; ++f) xr[f] = hs[j * 65 + c * 16 + f];
#pragma unroll
      for (int ii = 0; ii < 16; ++ii)
#pragma unroll
        for (int f = 0; f < 16; ++f)
          acc[ii] += xr[f] * wsh[(c * 16 + f) * 64 + g * 16 + ii];
    }
#pragma unroll
    for (int ii = 0; ii < 16; ++ii) dst[(kq * 16 + ii) * 8] = f2bf(acc[ii]);
  }
  // pass 4 (b==0 blocks): pool partials over our 64 nodes, all (bb,e)
  if (b == 0) {
#pragma unroll
    for (int part = 0; part < 2; ++part) {
      const int col = part * 256 + tid;
      const int bb = col >> 6, e = col & 63;
      float mx = -3.4e38f;
      for (int n = 0; n < 64; ++n) {
        float v = H[((long)bb * NN + j0 + n) * 64 + e];
        mx = fmaxf(mx, (v - sm[n]) * srs[n]);
      }
      PP[(long)jc * 512 + col] = mx;
    }
  }
}

extern "C" void kernel_launch(void* const* d_in, const int* in_sizes, int n_in,
                              void* d_out, int out_size, void* d_ws,
                              size_t ws_size, hipStream_t stream) {
  const float* x = (const float*)d_in[0];
  const int* rel = (const int*)d_in[1];
  // d_in[2] (adj) unread: adj == (rel > 0) == union bitplane
  const float* w_first = (const float*)d_in[3];
  const float* b_first = (const float*)d_in[4];
  const float* w_block = (const float*)d_in[5];
  const float* b_block = (const float*)d_in[6];
  const float* w_last = (const float*)d_in[7];
  const float* b_last = (const float*)d_in[8];
  const float* w_map = (const float*)d_in[9];
  const float* b_map = (const float*)d_in[10];
  float* out = (float*)d_out;

  char* ws = (char*)d_ws;
  const size_t MB = 1024 * 1024;
  unsigned* PLANES_U = (unsigned*)(ws);                  // 4 MiB union plane
  unsigned short* XWS = (unsigned short*)(ws + 4 * MB);  // 6 MiB
  float* H = (float*)(ws + 10 * MB);                     // 4 MiB
  float* PP1 = (float*)(ws + 14 * MB);                   // 64 KiB
  float* PP2 = (float*)(ws + 15 * MB);                   // 64 KiB
  float* PART3 = (float*)(ws + 16 * MB);                 // 64 KiB
  unsigned* DONE = (unsigned*)(ws + 17 * MB);            // 4 B

  // ---- XW(layer1) precompute (also zeros DONE) ----
  k_xw1<<<768, 256, 0, stream>>>(x, w_first, XWS, DONE);
  // ---- layer 1: rel-direct gemm (pack fused; writes union plane) ----
  k_gemm_rel<<<256, 512, 0, stream>>>(rel, XWS, b_first, H, PLANES_U);
  k_xwh_bn<<<256, 256, 0, stream>>>(H, w_block, XWS, PP1);
  // ---- layer 2 ----
  k_gemm_u<true, false><<<256, 512, 0, stream>>>(
      PLANES_U, XWS, b_block, H, nullptr, nullptr, nullptr, nullptr, nullptr,
      nullptr, nullptr);
  k_xwh_bn<<<256, 256, 0, stream>>>(H, w_last, XWS, PP2);
  // ---- layer 3 (fused L2norm + pool3 + last-block tail) ----
  k_gemm_u<false, true><<<256, 512, 0, stream>>>(
      PLANES_U, XWS, b_last, nullptr, PART3, PP1, PP2, out, w_map, b_map,
      DONE);
}